// Round 1
// 924.850 us; speedup vs baseline: 1.0322x; 1.0322x over previous
//
#include <hip/hip_runtime.h>
#include <hip/hip_bf16.h>

typedef __bf16 bf16;
typedef __bf16 bf16x8 __attribute__((ext_vector_type(8)));
typedef float f32x4 __attribute__((ext_vector_type(4)));

#define B_SZ 4
#define S_SZ 2048
#define DIN 4096
#define DOUT 4096
#define NAD 8
#define RNK 64
#define M_TOT (B_SZ * S_SZ)   // 8192
#define N1 (3 * NAD * RNK)    // 1536
#define K1 DIN                // 4096
#define K2 (NAD * RNK)        // 512

static __device__ __forceinline__ void async_cp16(const void* g, void* l) {
  __builtin_amdgcn_global_load_lds(
      (__attribute__((address_space(1))) void*)g,
      (__attribute__((address_space(3))) void*)l,
      16, 0, 0);
}

// ---------------------------------------------------------------- cast x -> bf16
__global__ __launch_bounds__(256) void cast_x_kernel(const float* __restrict__ x,
                                                     bf16* __restrict__ xb) {
  size_t i = ((size_t)blockIdx.x * 256 + threadIdx.x) * 8;
  float4 u = *(const float4*)(x + i);
  float4 v = *(const float4*)(x + i + 4);
  bf16x8 o;
  o[0] = (bf16)u.x; o[1] = (bf16)u.y; o[2] = (bf16)u.z; o[3] = (bf16)u.w;
  o[4] = (bf16)v.x; o[5] = (bf16)v.y; o[6] = (bf16)v.z; o[7] = (bf16)v.w;
  *(bf16x8*)(xb + i) = o;
}

// --------------------------------------------- pack A weights: [n][k][r] -> At[c][k]
__global__ __launch_bounds__(256) void pack_a_kernel(const float* __restrict__ qA,
                                                     const float* __restrict__ kA,
                                                     const float* __restrict__ vA,
                                                     bf16* __restrict__ At) {
  __shared__ bf16 t[64][65];
  const int ktile = blockIdx.x;  // 0..63
  const int n = blockIdx.y;      // 0..7
  const int comp = blockIdx.z;   // 0..2
  const float* src = (comp == 0) ? qA : (comp == 1) ? kA : vA;
  src += (size_t)n * (DIN * RNK) + (size_t)ktile * 64 * RNK;
  const int tid = threadIdx.x;
  const int r = tid & 63, kq = tid >> 6;
#pragma unroll
  for (int i = 0; i < 16; ++i) {
    int kk = kq + i * 4;
    t[r][kk] = (bf16)src[(size_t)kk * RNK + r];
  }
  __syncthreads();
  bf16* dst = At + (size_t)(comp * 512 + n * 64) * K1 + ktile * 64;
  const int kk2 = tid & 63, rq = tid >> 6;
#pragma unroll
  for (int i = 0; i < 16; ++i) {
    int rr = rq + i * 4;
    dst[(size_t)rr * K1 + kk2] = t[rr][kk2];
  }
}

// --------------------------------------------- pack B weights: [k][o] -> Bt[c][o][k]
__global__ __launch_bounds__(256) void pack_b_kernel(const float* __restrict__ qB,
                                                     const float* __restrict__ kB,
                                                     const float* __restrict__ vB,
                                                     bf16* __restrict__ Bt) {
  __shared__ bf16 t[64][65];
  const int otile = blockIdx.x;  // 0..63
  const int ktile = blockIdx.y;  // 0..7
  const int comp = blockIdx.z;
  const float* src = (comp == 0) ? qB : (comp == 1) ? kB : vB;
  src += (size_t)ktile * 64 * DOUT + (size_t)otile * 64;
  const int tid = threadIdx.x;
  const int o = tid & 63, kq = tid >> 6;
#pragma unroll
  for (int i = 0; i < 16; ++i) {
    int kk = kq + i * 4;
    t[o][kk] = (bf16)src[(size_t)kk * DOUT + o];
  }
  __syncthreads();
  bf16* dst = Bt + (size_t)comp * DOUT * K2 + (size_t)otile * 64 * K2 + ktile * 64;
  const int kk2 = tid & 63, oq = tid >> 6;
#pragma unroll
  for (int i = 0; i < 16; ++i) {
    int oo = oq + i * 4;
    dst[(size_t)oo * K2 + kk2] = t[oo][kk2];
  }
}

// ===================================================================== GEMM core
// 256x256 tile, BK=32, 512 threads (8 waves, 2M x 4N), per-wave 128x64 output.
// Ring-4 LDS buffers [256][32] bf16 per operand (128 KiB total), staged with
// global_load_lds (linear dest) + inverse-XOR-swizzled global source; ds_read
// side applies chunk ^= (row>>1)&3  -> 2-way (free) bank access.
// Schedule: 2 phases per K-tile, counted s_waitcnt vmcnt(8) at tile boundary
// only (loads for tiles kt+2/kt+3 stay in flight across barriers), raw
// s_barrier, s_setprio(1) around MFMA clusters.
static constexpr int TB = 256 * 32;  // bf16 per ring buffer

template <int KT>
static __device__ __forceinline__ void gemm_core(
    const bf16* __restrict__ aP,   // A tile base: row-major [256][KT]
    const bf16* __restrict__ bP,   // B tile base: row-major [256][KT] (B^T layout)
    bf16* __restrict__ As, bf16* __restrict__ Bs,
    f32x4 (&acc)[8][4]) {
  constexpr int NT = KT / 32;
  const int tid = threadIdx.x;
  const int wid = tid >> 6, lane = tid & 63;
  const int wm = wid >> 2, wn = wid & 3;
  const int lrow = lane & 15, quad = lane >> 4;
  const int srow = tid >> 2;      // staging row 0..127 (within 128-row block)
  const int cphys = tid & 3;      // physical 16B chunk this lane fills
  const int ldsW = wid * 512;     // wave-uniform bf16 offset of wave's segment

  auto stA = [&](int t) {
    if (t < NT) {
      const bf16* s = aP + (size_t)t * 32;
      bf16* d = As + (t & 3) * TB;
#pragma unroll
      for (int n = 0; n < 2; ++n) {
        const int row = n * 128 + srow;
        const int c = cphys ^ ((row >> 1) & 3);   // inverse swizzle on source
        async_cp16(s + (size_t)row * KT + c * 8, d + n * 4096 + ldsW);
      }
    }
  };
  auto stB = [&](int t) {
    if (t < NT) {
      const bf16* s = bP + (size_t)t * 32;
      bf16* d = Bs + (t & 3) * TB;
#pragma unroll
      for (int n = 0; n < 2; ++n) {
        const int row = n * 128 + srow;
        const int c = cphys ^ ((row >> 1) & 3);
        async_cp16(s + (size_t)row * KT + c * 8, d + n * 4096 + ldsW);
      }
    }
  };
  auto rdA = [&](int buf, int qm, bf16x8 (&a)[4]) {
#pragma unroll
    for (int i = 0; i < 4; ++i) {
      const int r = wm * 128 + qm * 64 + i * 16 + lrow;
      const int c = quad ^ ((r >> 1) & 3);        // swizzled read
      a[i] = *(const bf16x8*)(As + buf * TB + r * 32 + c * 8);
    }
  };
  auto rdB = [&](int buf, bf16x8 (&b)[4]) {
#pragma unroll
    for (int j = 0; j < 4; ++j) {
      const int r = wn * 64 + j * 16 + lrow;
      const int c = quad ^ ((r >> 1) & 3);
      b[j] = *(const bf16x8*)(Bs + buf * TB + r * 32 + c * 8);
    }
  };

  // Prologue: stage tiles 0,1,2 (tile-order pinned by memory-clobber fences).
  stA(0); stB(0);
  asm volatile("" ::: "memory");
  stA(1); stB(1);
  asm volatile("" ::: "memory");
  stA(2); stB(2);
  asm volatile("s_waitcnt vmcnt(8)" ::: "memory");  // tile 0 resident
  __builtin_amdgcn_s_barrier();

  for (int kt = 0; kt < NT; ++kt) {
    const int buf = kt & 3;
    bf16x8 a0[4], a1[4], b0[4];
    // ---- phase 1: read qm=0 A-frags + all B-frags, stage A of tile kt+3
    rdA(buf, 0, a0);
    rdB(buf, b0);
    stA(kt + 3);
    __builtin_amdgcn_s_barrier();
    __builtin_amdgcn_s_setprio(1);
#pragma unroll
    for (int i = 0; i < 4; ++i)
#pragma unroll
      for (int j = 0; j < 4; ++j)
        acc[i][j] = __builtin_amdgcn_mfma_f32_16x16x32_bf16(a0[i], b0[j], acc[i][j], 0, 0, 0);
    __builtin_amdgcn_s_setprio(0);
    // ---- phase 2: read qm=1 A-frags, stage B of tile kt+3, tile boundary
    rdA(buf, 1, a1);
    stB(kt + 3);
    // Retire this wave's LDS reads before the boundary barrier (so buffers can
    // be overwritten by other waves' next-iteration staging), then counted
    // vmcnt: keep tiles kt+2,kt+3 (8 insts) in flight, guarantee kt+1 resident.
    asm volatile("s_waitcnt lgkmcnt(0)" ::: "memory");
    {
      const int rem = NT - 1 - kt;
      if (rem >= 3) {
        asm volatile("s_waitcnt vmcnt(8)" ::: "memory");
      } else if (rem == 2) {
        asm volatile("s_waitcnt vmcnt(4)" ::: "memory");
      } else if (rem == 1) {
        asm volatile("s_waitcnt vmcnt(0)" ::: "memory");
      }
    }
    __builtin_amdgcn_s_barrier();
    __builtin_amdgcn_s_setprio(1);
#pragma unroll
    for (int i = 0; i < 4; ++i)
#pragma unroll
      for (int j = 0; j < 4; ++j)
        acc[4 + i][j] = __builtin_amdgcn_mfma_f32_16x16x32_bf16(a1[i], b0[j], acc[4 + i][j], 0, 0, 0);
    __builtin_amdgcn_s_setprio(0);
  }
}

// ----------------------------------------------------------- GEMM1: H = X @ Acat
__global__ __launch_bounds__(512, 2) void gemm1_kernel(
    const bf16* __restrict__ Xb,   // [8192][4096]
    const bf16* __restrict__ At,   // [1536][4096]
    bf16* __restrict__ H,          // [3][8192][512]
    const float* __restrict__ masks,
    const float* __restrict__ scaling) {
  __shared__ __align__(16) bf16 As[4 * TB];
  __shared__ __align__(16) bf16 Bs[4 * TB];
  const int tm = blockIdx.x, tn = blockIdx.y;
  f32x4 acc[8][4] = {};
  gemm_core<K1>(Xb + (size_t)(tm * 256) * K1, At + (size_t)(tn * 256) * K1, As, Bs, acc);

  const int tid = threadIdx.x, wid = tid >> 6, lane = tid & 63;
  const int wm = wid >> 2, wn = wid & 3;
  const int lrow = lane & 15, quad = lane >> 4;
  const int col0 = tn * 256 + wn * 64;   // 64-aligned -> one adapter per wave
  const int comp = col0 >> 9;
  const int n_ad = (col0 >> 6) & 7;
  const int b = tm >> 3;                 // 256-row tiles, 2048 rows per batch
  const float coef = scaling[n_ad] * masks[n_ad * 4 + b];
  bf16* hP = H + (size_t)comp * (M_TOT * K2);
#pragma unroll
  for (int i = 0; i < 8; ++i) {
#pragma unroll
    for (int j = 0; j < 4; ++j) {
      const int kc = (col0 + j * 16 + lrow) & 511;
#pragma unroll
      for (int e = 0; e < 4; ++e) {
        const int row = tm * 256 + wm * 128 + i * 16 + quad * 4 + e;
        hP[(size_t)row * K2 + kc] = (bf16)(acc[i][j][e] * coef);
      }
    }
  }
}

// ------------------------------------------------- GEMM2: out_c = H_c @ Bcat_c
__global__ __launch_bounds__(512, 2) void gemm2_kernel(
    const bf16* __restrict__ H,    // [3][8192][512]
    const bf16* __restrict__ Bt,   // [3][4096][512]
    float* __restrict__ out) {     // [8192][12288]
  __shared__ __align__(16) bf16 As[4 * TB];
  __shared__ __align__(16) bf16 Bs[4 * TB];
  const int tm = blockIdx.x, tn = blockIdx.y, comp = blockIdx.z;
  f32x4 acc[8][4] = {};
  gemm_core<K2>(H + (size_t)comp * (M_TOT * K2) + (size_t)(tm * 256) * K2,
                Bt + (size_t)comp * (DOUT * K2) + (size_t)(tn * 256) * K2, As, Bs, acc);

  const int tid = threadIdx.x, wid = tid >> 6, lane = tid & 63;
  const int wm = wid >> 2, wn = wid & 3;
  const int lrow = lane & 15, quad = lane >> 4;
  float* oP = out + (size_t)comp * DOUT;
#pragma unroll
  for (int i = 0; i < 8; ++i) {
#pragma unroll
    for (int j = 0; j < 4; ++j) {
      const int col = tn * 256 + wn * 64 + j * 16 + lrow;
#pragma unroll
      for (int e = 0; e < 4; ++e) {
        const int row = tm * 256 + wm * 128 + i * 16 + quad * 4 + e;
        oP[(size_t)row * (3 * DOUT) + col] = acc[i][j][e];
      }
    }
  }
}

extern "C" void kernel_launch(void* const* d_in, const int* in_sizes, int n_in,
                              void* d_out, int out_size, void* d_ws, size_t ws_size,
                              hipStream_t stream) {
  (void)in_sizes; (void)n_in; (void)out_size; (void)ws_size;
  const float* x       = (const float*)d_in[0];
  // d_in[1] is the zeros "output" buffer -- unused.
  const float* masks   = (const float*)d_in[2];
  const float* scaling = (const float*)d_in[3];
  const float* qA      = (const float*)d_in[4];
  const float* qB      = (const float*)d_in[5];
  const float* kA      = (const float*)d_in[6];
  const float* kB      = (const float*)d_in[7];
  const float* vA      = (const float*)d_in[8];
  const float* vB      = (const float*)d_in[9];
  float* out = (float*)d_out;

  char* ws = (char*)d_ws;
  bf16* xb = (bf16*)ws;                                   // 8192*4096*2   = 64 MiB
  bf16* At = (bf16*)(ws + 67108864);                      // 1536*4096*2   = 12 MiB
  bf16* Bt = (bf16*)(ws + 67108864 + 12582912);           // 3*4096*512*2  = 12 MiB
  bf16* H  = (bf16*)(ws + 67108864 + 2 * 12582912);       // 3*8192*512*2  = 24 MiB

  cast_x_kernel<<<(M_TOT * (size_t)DIN) / 8 / 256, 256, 0, stream>>>(x, xb);
  pack_a_kernel<<<dim3(64, 8, 3), 256, 0, stream>>>(qA, kA, vA, At);
  pack_b_kernel<<<dim3(64, 8, 3), 256, 0, stream>>>(qB, kB, vB, Bt);
  gemm1_kernel<<<dim3(M_TOT / 256, N1 / 256), 512, 0, stream>>>(xb, At, H, masks, scaling);
  gemm2_kernel<<<dim3(M_TOT / 256, DOUT / 256, 3), 512, 0, stream>>>(H, Bt, out);
}